// Round 10
// baseline (2617.914 us; speedup 1.0000x reference)
//
#include <hip/hip_runtime.h>
#include <stdint.h>
#include <math.h>

// Problem constants (B, H, T) = (16, 2048, 512)
#define Hdim   2048
#define Bdim   16
#define Tsteps 512
#define NWG    64    // workgroups; each owns KC columns of h (halves LLC all-to-all vs R6)
#define TPB    512   // 8 waves -> 8 chunks/wave -> registers fit (R5 lesson)
#define KC     32    // h-columns per WG  (NWG*KC == Hdim)
#define NCHUNK 8     // K-chunks of 32 per wave (wave K-range = 256)
#define FLAGSTRIDE 32  // uint32s between per-WG flags (128B) — separate lines
#define HBYTES (Bdim * Hdim * 2)   // one h buffer in bytes (fragment-major bf16)

typedef __attribute__((ext_vector_type(8))) short short8_t;  // 8 bf16 (4 VGPRs)
typedef __attribute__((ext_vector_type(4))) float f32x4;     // MFMA C/D
typedef __attribute__((ext_vector_type(4))) unsigned int u32x4;

__device__ __forceinline__ short f2bf(float x) {
  uint32_t u = __builtin_bit_cast(uint32_t, x);
  u += 0x7fffu + ((u >> 16) & 1u);   // RNE
  return (short)(u >> 16);
}

__device__ __forceinline__ short8_t load8_bf(const float* __restrict__ p) {
  short8_t r;
#pragma unroll
  for (int j = 0; j < 8; ++j) r[j] = f2bf(p[j]);
  return r;
}

// ---- flag barrier helpers (R6-proven protocol) ----
// publish: explicit vmcnt(0) drains this wave's h-stores (inline-asm ones the
// compiler doesn't track), __syncthreads joins all 8 waves, then one thread
// stores this WG's arrival flag (own 128B line -> no inter-WG store contention).
__device__ __forceinline__ void publish(uint32_t* flags, int wg, int tid, uint32_t n) {
  asm volatile("s_waitcnt vmcnt(0)" ::: "memory");
  __syncthreads();
  if (tid == 0)
    __hip_atomic_store(flags + wg * FLAGSTRIDE, n, __ATOMIC_RELAXED, __HIP_MEMORY_SCOPE_AGENT);
}

// wait_eighth: wave w only consumes h columns [256w, 256w+256), produced by
// WGs [8w, 8w+8). Poll exactly those 8 separated flag lines and proceed.
// RULE (R8 lesson): every load issued after this wait may depend ONLY on those
// 8 producers. (R8's pdot load violated this -> race -> absmax fail.)
// Buffer-reuse safety: publish() runs __syncthreads() BEFORE the flag store, so
// WG A stores h_{i+1} (overwriting h_{i-1}'s parity) only after all 8 of A's
// waves saw their producer eighths at >= i+1 -- union = all 64 WGs published
// h_i, which they do only after their step-(i-1) reads of h_{i-1} completed.
__device__ __forceinline__ void wait_eighth(const uint32_t* flags, int wave, int lane, uint32_t n) {
  if (lane < 8) {
    const uint32_t* f = flags + (wave * 8 + lane) * FLAGSTRIDE;
    while (__hip_atomic_load(f, __ATOMIC_RELAXED, __HIP_MEMORY_SCOPE_AGENT) < n) {
      __builtin_amdgcn_s_sleep(1);
    }
  }
  __builtin_amdgcn_sched_barrier(0);
}

// ---- h buffer layout (R3): MFMA-fragment-major ----
// Byte offset of (b, col): (col>>3)*256 + b*16 + (col&7)*2. Consumer wave reads
// per 32-col chunk a contiguous 1KB span (lane*16B), uncached, line-coalesced.
__device__ __forceinline__ void publish_h(uint32_t* hbuf32, int buf,
                                          int eb, int ekc, int ecol, float h_own) {
  uint32_t mybits = (uint32_t)(uint16_t)f2bf(h_own);
  uint32_t n1 = (uint32_t)__shfl_xor((int)mybits, 1, 64);
  uint32_t a  = (mybits & 0xffffu) | (n1 << 16);            // cols j, j+1
  uint32_t b  = (uint32_t)__shfl_xor((int)a, 2, 64);        // cols j+2, j+3
  uint32_t c4 = (uint32_t)__shfl_xor((int)a, 4, 64);        // cols j+4, j+5
  uint32_t d  = (uint32_t)__shfl_xor((int)b, 4, 64);        // cols j+6, j+7
  if ((ekc & 7) == 0) {
    u32x4 q; q.x = a; q.y = b; q.z = c4; q.w = d;
    char* dst = (char*)hbuf32 + (size_t)buf * HBYTES
              + ((size_t)(ecol >> 3) * 256 + (size_t)eb * 16);
    asm volatile("global_store_dwordx4 %0, %1, off sc0 sc1" :: "v"(dst), "v"(q) : "memory");
  }
}

__global__ void __launch_bounds__(TPB, 1) traj_kernel(
    const float* __restrict__ traj_z, const float* __restrict__ traj_input,
    const float* __restrict__ w_ih, const float* __restrict__ b_ih,
    const float* __restrict__ w_hh, const float* __restrict__ b_hh,
    const float* __restrict__ w_traj, const float* __restrict__ b_traj,
    float* __restrict__ out, uint32_t* __restrict__ hbuf32, uint32_t* __restrict__ flags)
{
  const int tid  = threadIdx.x;
  const int wg   = blockIdx.x;
  const int wave = tid >> 6;        // 0..7
  const int lane = tid & 63;
  const int ln16 = lane & 15;       // MFMA: A row (batch) / B col (tile row) / D col
  const int quad = lane >> 4;
  const int colbase = wg * KC;
  const int kwave   = wave * (Hdim / 8);   // this wave's K-eighth (256)
  const int gcbase  = wave * NCHUNK;       // first global 32-col chunk index

  // LDS: 64KB s_wn1 + 48KB s_red + 0.5KB s_x3 = 112.5KB (of 160)
  __shared__ short8_t s_wn1[64][64];            // [gc][lane]: gate-n tile1 B-frags
  __shared__ float s_red[8][3][2][16][16];      // wave, gate, tile, m(batch), n
  __shared__ float s_x3[8][16];                 // per-wave w_traj dot partial

  // ---- build s_wn1 (gate-n, cols colbase+16..+31, all K) ----
  for (int idx = tid; idx < 64 * 64; idx += TPB) {
    const int gc = idx >> 6, l = idx & 63;
    const int col = colbase + 16 + (l & 15);
    const int k0  = gc * 32 + (l >> 4) * 8;
    s_wn1[gc][l] = load8_bf(w_hh + (size_t)(2 * Hdim + col) * Hdim + k0);
  }

  // ---- register B-fragments: 5 arrays x 8 chunks = 160 VGPR + wt 32 VGPR ----
  short8_t fr0[NCHUNK], fz0[NCHUNK], fn0[NCHUNK], fr1[NCHUNK], fz1[NCHUNK], wt[NCHUNK];
#pragma unroll
  for (int c = 0; c < NCHUNK; ++c) {
    const int k0 = kwave + c * 32 + quad * 8;
    fr0[c] = load8_bf(w_hh + (size_t)(0 * Hdim + colbase + ln16) * Hdim + k0);
    fz0[c] = load8_bf(w_hh + (size_t)(1 * Hdim + colbase + ln16) * Hdim + k0);
    fn0[c] = load8_bf(w_hh + (size_t)(2 * Hdim + colbase + ln16) * Hdim + k0);
    fr1[c] = load8_bf(w_hh + (size_t)(0 * Hdim + colbase + 16 + ln16) * Hdim + k0);
    fz1[c] = load8_bf(w_hh + (size_t)(1 * Hdim + colbase + 16 + ln16) * Hdim + k0);
    short8_t g = {0, 0, 0, 0, 0, 0, 0, 0};
    if (ln16 == 0) g = load8_bf(w_traj + k0);   // w_traj tile: single nonzero row
    wt[c] = g;
  }

  // ---- per-thread epilogue state: thread owns exactly one column ----
  const int eb   = tid >> 5;        // batch 0..15
  const int ekc  = tid & 31;        // col within WG slice
  const int ecol = colbase + ekc;
  const float wih_r = w_ih[ecol], wih_z = w_ih[Hdim + ecol], wih_n = w_ih[2 * Hdim + ecol];
  const float br  = b_ih[ecol] + b_hh[ecol];
  const float bz  = b_ih[Hdim + ecol] + b_hh[Hdim + ecol];
  const float bin = b_ih[2 * Hdim + ecol];
  const float bhn = b_hh[2 * Hdim + ecol];
  const float bt  = b_traj[0];
  float h_own = traj_z[eb * Hdim + ecol];
  float x_reg = traj_input[eb * Tsteps];

  // ---- publish h_0 ----
  publish_h(hbuf32, 0, eb, ekc, ecol, h_own);
  publish(flags, wg, tid, 1);

  for (int i = 0; i <= Tsteps; ++i) {
    wait_eighth(flags, wave, lane, (uint32_t)(i + 1));  // my producers published h_i

    // harden vmcnt bookkeeping (also drains wg0's prior out-store)
    asm volatile("s_waitcnt vmcnt(0)" ::: "memory");

    // h_i A-fragments: 8 coalesced uncached 16B loads; counted-vmcnt groups
    // overlap the 7-MFMA chains with the load tail (R6-proven).
    const char* hbase = (const char*)hbuf32 + (size_t)(i & 1) * HBYTES
                      + (size_t)(kwave >> 5) * 1024 + (size_t)lane * 16;
    short8_t af[NCHUNK];
#pragma unroll
    for (int c = 0; c < NCHUNK; ++c) {
      asm volatile("global_load_dwordx4 %0, %1, off sc0 sc1"
                   : "=v"(af[c]) : "v"(hbase + (size_t)c * 1024));
    }

    f32x4 ar0 = {0.f, 0.f, 0.f, 0.f}, az0 = ar0, an0 = ar0;
    f32x4 ar1 = ar0, az1 = ar0, an1 = ar0, a3 = ar0;

    // double-buffered LDS reads of the 6th tile (issue under the vmcnt waits)
    short8_t wnA = s_wn1[gcbase + 0][lane];
    short8_t wnB = s_wn1[gcbase + 1][lane];

#define CHAIN(c, wn)                                                            \
    ar0 = __builtin_amdgcn_mfma_f32_16x16x32_bf16(af[c], fr0[c], ar0, 0, 0, 0); \
    az0 = __builtin_amdgcn_mfma_f32_16x16x32_bf16(af[c], fz0[c], az0, 0, 0, 0); \
    an0 = __builtin_amdgcn_mfma_f32_16x16x32_bf16(af[c], fn0[c], an0, 0, 0, 0); \
    ar1 = __builtin_amdgcn_mfma_f32_16x16x32_bf16(af[c], fr1[c], ar1, 0, 0, 0); \
    az1 = __builtin_amdgcn_mfma_f32_16x16x32_bf16(af[c], fz1[c], az1, 0, 0, 0); \
    an1 = __builtin_amdgcn_mfma_f32_16x16x32_bf16(af[c], (wn),  an1, 0, 0, 0);  \
    a3  = __builtin_amdgcn_mfma_f32_16x16x32_bf16(af[c], wt[c], a3,  0, 0, 0);

    asm volatile("s_waitcnt vmcnt(6)" ::: "memory");
    __builtin_amdgcn_sched_barrier(0);
    CHAIN(0, wnA) CHAIN(1, wnB)
    wnA = s_wn1[gcbase + 2][lane]; wnB = s_wn1[gcbase + 3][lane];
    asm volatile("s_waitcnt vmcnt(4)" ::: "memory");
    __builtin_amdgcn_sched_barrier(0);
    CHAIN(2, wnA) CHAIN(3, wnB)
    wnA = s_wn1[gcbase + 4][lane]; wnB = s_wn1[gcbase + 5][lane];
    asm volatile("s_waitcnt vmcnt(2)" ::: "memory");
    __builtin_amdgcn_sched_barrier(0);
    CHAIN(4, wnA) CHAIN(5, wnB)
    wnA = s_wn1[gcbase + 6][lane]; wnB = s_wn1[gcbase + 7][lane];
    asm volatile("s_waitcnt vmcnt(0)" ::: "memory");
    __builtin_amdgcn_sched_barrier(0);
    CHAIN(6, wnA) CHAIN(7, wnB)
#undef CHAIN

    // D[m][n]: n = lane&15, m = quad*4 + r
#pragma unroll
    for (int r = 0; r < 4; ++r) {
      const int m = quad * 4 + r;
      s_red[wave][0][0][m][ln16] = ar0[r]; s_red[wave][0][1][m][ln16] = ar1[r];
      s_red[wave][1][0][m][ln16] = az0[r]; s_red[wave][1][1][m][ln16] = az1[r];
      s_red[wave][2][0][m][ln16] = an0[r]; s_red[wave][2][1][m][ln16] = an1[r];
    }
    if (ln16 == 0) {
#pragma unroll
      for (int r = 0; r < 4; ++r) s_x3[wave][quad * 4 + r] = a3[r];
    }
    __syncthreads();

    // x_i = x_{i-1} + dot(h_i, w_traj) + bt : sum the 8 per-wave K-eighth
    // partials in fixed order — identical values & order in every thread of
    // every WG -> bitwise-identical x_reg. Depends only on h_i (safe with
    // eighth-waits; the barrier above joins all 8 waves = all 64 flags seen).
    if (i > 0) {
      float xd = s_x3[0][eb];
#pragma unroll
      for (int w = 1; w < 8; ++w) xd += s_x3[w][eb];
      x_reg += xd + bt;
    }

    if (i == Tsteps) {
      if (wg == 0 && ekc == 0) out[eb * Tsteps + (i - 1)] = x_reg;
      break;
    }

    // gates for (eb, ecol): tile tt = ekc>>4, col-in-tile nn_ = ekc&15
    const int tt = ekc >> 4, nn_ = ekc & 15;
    const float gr = ((s_red[0][0][tt][eb][nn_] + s_red[1][0][tt][eb][nn_]) + (s_red[2][0][tt][eb][nn_] + s_red[3][0][tt][eb][nn_]))
                   + ((s_red[4][0][tt][eb][nn_] + s_red[5][0][tt][eb][nn_]) + (s_red[6][0][tt][eb][nn_] + s_red[7][0][tt][eb][nn_]));
    const float gz = ((s_red[0][1][tt][eb][nn_] + s_red[1][1][tt][eb][nn_]) + (s_red[2][1][tt][eb][nn_] + s_red[3][1][tt][eb][nn_]))
                   + ((s_red[4][1][tt][eb][nn_] + s_red[5][1][tt][eb][nn_]) + (s_red[6][1][tt][eb][nn_] + s_red[7][1][tt][eb][nn_]));
    const float gn = ((s_red[0][2][tt][eb][nn_] + s_red[1][2][tt][eb][nn_]) + (s_red[2][2][tt][eb][nn_] + s_red[3][2][tt][eb][nn_]))
                   + ((s_red[4][2][tt][eb][nn_] + s_red[5][2][tt][eb][nn_]) + (s_red[6][2][tt][eb][nn_] + s_red[7][2][tt][eb][nn_]));

    const float x  = x_reg;
    const float rr = 1.f / (1.f + expf(-(x * wih_r + br + gr)));
    const float zz = 1.f / (1.f + expf(-(x * wih_z + bz + gz)));
    const float nv = tanhf(x * wih_n + bin + rr * (gn + bhn));
    h_own = (1.f - zz) * nv + zz * h_own;

    // publish h_{i+1}, then flag; wg0's out-store LAST (off the critical path)
    publish_h(hbuf32, (i + 1) & 1, eb, ekc, ecol, h_own);
    publish(flags, wg, tid, (uint32_t)(i + 2));
    if (wg == 0 && i > 0 && ekc == 0) out[eb * Tsteps + (i - 1)] = x_reg;
  }
}

extern "C" void kernel_launch(void* const* d_in, const int* in_sizes, int n_in,
                              void* d_out, int out_size, void* d_ws, size_t ws_size,
                              hipStream_t stream) {
  const float* traj_z     = (const float*)d_in[0];
  const float* traj_input = (const float*)d_in[1];
  const float* w_ih   = (const float*)d_in[2];
  const float* b_ih   = (const float*)d_in[3];
  const float* w_hh   = (const float*)d_in[4];
  const float* b_hh   = (const float*)d_in[5];
  const float* w_traj = (const float*)d_in[6];
  const float* b_traj = (const float*)d_in[7];
  float* out = (float*)d_out;

  uint8_t*  ws    = (uint8_t*)d_ws;
  uint32_t* flags = (uint32_t*)ws;                 // 64*128B = 8 KB (16 KB reserved)
  uint32_t* hbuf  = (uint32_t*)(ws + 16384);       // 2*64KB = 128 KB

  (void)hipMemsetAsync(flags, 0, NWG * FLAGSTRIDE * 4, stream);
  hipLaunchKernelGGL(traj_kernel, dim3(NWG), dim3(TPB), 0, stream,
                     traj_z, traj_input, w_ih, b_ih, w_hh, b_hh, w_traj, b_traj,
                     out, hbuf, flags);
}

// Round 12
// 1685.566 us; speedup vs baseline: 1.5531x; 1.5531x over previous
//
#include <hip/hip_runtime.h>
#include <stdint.h>
#include <math.h>

// Problem constants (B, H, T) = (16, 2048, 512)
#define Hdim   2048
#define Bdim   16
#define Tsteps 512
#define NWG    128   // workgroups; each owns KC columns of h (R6-proven optimum)
#define TPB    256   // 4 waves
#define KC     16    // h-columns per WG  (NWG*KC == Hdim)
#define NCHUNK 16    // K-chunks of 32 per wave (wave K-range = 512)
#define FLAGSTRIDE 32  // uint32s between per-WG flags (128B) — separate lines
#define NREP   4     // flag replicas: cuts readers/line 128 -> 32 (hot-line fix)
#define HBYTES (Bdim * Hdim * 2)   // one h buffer in bytes (fragment-major bf16)

typedef __attribute__((ext_vector_type(8))) short short8_t;  // 8 bf16 (4 VGPRs)
typedef __attribute__((ext_vector_type(4))) float f32x4;     // MFMA C/D
typedef __attribute__((ext_vector_type(4))) unsigned int u32x4;

__device__ __forceinline__ short f2bf(float x) {
  uint32_t u = __builtin_bit_cast(uint32_t, x);
  u += 0x7fffu + ((u >> 16) & 1u);   // RNE
  return (short)(u >> 16);
}

__device__ __forceinline__ short8_t load8_bf(const float* __restrict__ p) {
  short8_t r;
#pragma unroll
  for (int j = 0; j < 8; ++j) r[j] = f2bf(p[j]);
  return r;
}

// ---- flag barrier helpers ----
// publish: explicit vmcnt(0) drains this wave's h-stores (inline-asm ones the
// compiler doesn't track), __syncthreads joins all waves, then threads 0..3
// store this WG's arrival flag to 4 REPLICA lines (all after the same barrier,
// so any replica >= n carries the full transitivity proof). Each replica line
// is polled by only 32 WGs -> 4x less reader contention on the hot line, and
// the flag store no longer queues behind 128 concurrent poll reads.
__device__ __forceinline__ void publish(uint32_t* flags, int wg, int tid, uint32_t n) {
  asm volatile("s_waitcnt vmcnt(0)" ::: "memory");
  __syncthreads();
  if (tid < NREP)
    __hip_atomic_store(flags + (tid * NWG + wg) * FLAGSTRIDE, n,
                       __ATOMIC_RELAXED, __HIP_MEMORY_SCOPE_AGENT);
}

// wait_quarter: wave w only consumes h columns [512w, 512w+512), produced by
// WGs [32w, 32w+32). Poll exactly those 32 separated flag lines (replica wg&3)
// and proceed straight to the loads -- no block-wide barrier. RULE (R8): every
// load issued after this wait depends ONLY on those 32 producers.
// Buffer-reuse safety: publish() runs __syncthreads() BEFORE the flag stores,
// so WG A stores h_{i+1} (overwriting h_{i-1}'s parity) only after all 4 of
// A's waves saw their producer quarters at >= i+1 -- union = all 128 WGs
// published h_i, which they do only after their step-(i-1) reads completed.
__device__ __forceinline__ void wait_quarter(const uint32_t* flags, int wg,
                                             int wave, int lane, uint32_t n) {
  if (lane < 32) {
    const uint32_t* f = flags + (((wg & (NREP - 1)) * NWG) + wave * 32 + lane) * FLAGSTRIDE;
    while (__hip_atomic_load(f, __ATOMIC_RELAXED, __HIP_MEMORY_SCOPE_AGENT) < n) {
      __builtin_amdgcn_s_sleep(1);
    }
  }
  __builtin_amdgcn_sched_barrier(0);
}

// ---- h buffer layout (R3): MFMA-fragment-major ----
// 16B block (gc*4 + quad)*16 + batch holds cols [gc*32+quad*8, +8) of one batch.
// Byte offset of (b, col): (col>>3)*256 + b*16 + (col&7)*2.
// Consumer wave reads per chunk a contiguous 1KB span (lane*16B), uncached.
__device__ __forceinline__ void publish_h(uint32_t* hbuf32, int buf,
                                          int eb, int ekc, int ecol, float h_own) {
  uint32_t mybits = (uint32_t)(uint16_t)f2bf(h_own);
  uint32_t n1 = (uint32_t)__shfl_xor((int)mybits, 1, 64);
  uint32_t a  = (mybits & 0xffffu) | (n1 << 16);            // cols j, j+1
  uint32_t b  = (uint32_t)__shfl_xor((int)a, 2, 64);        // cols j+2, j+3
  uint32_t c4 = (uint32_t)__shfl_xor((int)a, 4, 64);        // cols j+4, j+5
  uint32_t d  = (uint32_t)__shfl_xor((int)b, 4, 64);        // cols j+6, j+7
  if ((ekc & 7) == 0) {
    u32x4 q; q.x = a; q.y = b; q.z = c4; q.w = d;
    char* dst = (char*)hbuf32 + (size_t)buf * HBYTES
              + ((size_t)(ecol >> 3) * 256 + (size_t)eb * 16);
    asm volatile("global_store_dwordx4 %0, %1, off sc0 sc1" :: "v"(dst), "v"(q) : "memory");
  }
}

__global__ void __launch_bounds__(TPB, 1) traj_kernel(
    const float* __restrict__ traj_z, const float* __restrict__ traj_input,
    const float* __restrict__ w_ih, const float* __restrict__ b_ih,
    const float* __restrict__ w_hh, const float* __restrict__ b_hh,
    const float* __restrict__ w_traj, const float* __restrict__ b_traj,
    float* __restrict__ out, uint32_t* __restrict__ hbuf32, uint32_t* __restrict__ flags)
{
  const int tid  = threadIdx.x;
  const int wg   = blockIdx.x;
  const int wave = tid >> 6;
  const int lane = tid & 63;
  const int ln16 = lane & 15;       // MFMA: A row (batch) / B col (our 16 rows) / D col
  const int quad = lane >> 4;
  const int colbase = wg * KC;
  const int kwave   = wave * (Hdim / 4);   // this wave's K-quarter

  __shared__ float s_red[4][3][16][16];  // wave, gate-tile, m(batch), n(col)  = 12 KB
  __shared__ float s_x3[4][16];          // per-wave partial dot(h, w_traj) per batch

  // ---- preload w_hh slice as register-resident bf16 B-fragments ----
  // B[k][n]: n = lane&15 (row within tile), k = quad*8 + j within each 32-chunk.
  short8_t wf0[NCHUNK], wf1[NCHUNK], wf2[NCHUNK], wt[NCHUNK];
#pragma unroll
  for (int c = 0; c < NCHUNK; ++c) {
    const int k0 = kwave + c * 32 + quad * 8;
    wf0[c] = load8_bf(w_hh + (size_t)(0 * Hdim + colbase + ln16) * Hdim + k0); // r rows
    wf1[c] = load8_bf(w_hh + (size_t)(1 * Hdim + colbase + ln16) * Hdim + k0); // z rows
    wf2[c] = load8_bf(w_hh + (size_t)(2 * Hdim + colbase + ln16) * Hdim + k0); // n rows
    short8_t g = {0, 0, 0, 0, 0, 0, 0, 0};
    if (ln16 == 0) g = load8_bf(w_traj + k0);    // 4th tile: single w_traj row
    wt[c] = g;
  }

  // ---- per-thread epilogue constants: thread (eb, ekc) owns h[eb][colbase+ekc] ----
  const int eb   = tid >> 4;       // batch 0..15
  const int ekc  = tid & 15;       // col within WG slice
  const int ecol = colbase + ekc;
  const float wr = w_ih[ecol], wz = w_ih[Hdim + ecol], wn = w_ih[2 * Hdim + ecol];
  const float br = b_ih[ecol] + b_hh[ecol];                    // merged r biases
  const float bz = b_ih[Hdim + ecol] + b_hh[Hdim + ecol];      // merged z biases
  const float bin = b_ih[2 * Hdim + ecol];
  const float bhn = b_hh[2 * Hdim + ecol];                     // inside r*(...)
  const float bt  = b_traj[0];
  float h_own = traj_z[eb * Hdim + ecol];                      // fp32 own state
  float x_reg = traj_input[eb * Tsteps];                       // per-thread x for batch eb

  // ---- publish h_0 ----
  publish_h(hbuf32, 0, eb, ekc, ecol, h_own);
  publish(flags, wg, tid, 1);

  // step i: reads h_i, produces h_{i+1}; also dot(h_i, w_traj) -> x_i (i>=1).
  // out[:, i-1] = x_i. Extra iteration i==Tsteps computes only x_T -> out[:,T-1].
  for (int i = 0; i <= Tsteps; ++i) {
    // this wave's K-quarter producers have published h_i
    wait_quarter(flags, wg, wave, lane, (uint32_t)(i + 1));

    // harden vmcnt bookkeeping: everything older (incl. flag/out stores) is
    // drained, so after issuing the 16 af loads the outstanding count is 16.
    asm volatile("s_waitcnt vmcnt(0)" ::: "memory");

    // A-fragments of h_i: per chunk a contiguous 1KB span (lane*16B), one
    // dwordx4 sc0 sc1 per lane (uncached, reads the coherence point; fully
    // line-coalesced). All 16 issued, then counted-vmcnt groups overlap the
    // MFMA block with the load tail (R6-proven). sched_barrier after each wait
    // is REQUIRED: register-only MFMAs otherwise hoist past inline-asm waits.
    const char* hbase = (const char*)hbuf32 + (size_t)(i & 1) * HBYTES
                      + (size_t)(kwave >> 5) * 1024 + (size_t)lane * 16;
    short8_t af[NCHUNK];
#pragma unroll
    for (int c = 0; c < NCHUNK; ++c) {
      asm volatile("global_load_dwordx4 %0, %1, off sc0 sc1"
                   : "=v"(af[c]) : "v"(hbase + (size_t)c * 1024));
    }

    f32x4 a0 = {0.f, 0.f, 0.f, 0.f}, a1 = a0, a2 = a0, a3 = a0;

#define MFMA_GROUP(G, VM)                                                      \
    asm volatile("s_waitcnt vmcnt(" #VM ")" ::: "memory");                     \
    __builtin_amdgcn_sched_barrier(0);                                         \
    _Pragma("unroll")                                                          \
    for (int c = (G) * 4; c < (G) * 4 + 4; ++c) {                              \
      a0 = __builtin_amdgcn_mfma_f32_16x16x32_bf16(af[c], wf0[c], a0, 0, 0, 0);\
      a1 = __builtin_amdgcn_mfma_f32_16x16x32_bf16(af[c], wf1[c], a1, 0, 0, 0);\
      a2 = __builtin_amdgcn_mfma_f32_16x16x32_bf16(af[c], wf2[c], a2, 0, 0, 0);\
      a3 = __builtin_amdgcn_mfma_f32_16x16x32_bf16(af[c], wt[c],  a3, 0, 0, 0);\
    }

    MFMA_GROUP(0, 12)
    MFMA_GROUP(1, 8)
    MFMA_GROUP(2, 4)
    MFMA_GROUP(3, 0)
#undef MFMA_GROUP

    // D[m][n]: n = lane&15, m = quad*4 + r
#pragma unroll
    for (int r = 0; r < 4; ++r) {
      const int m = quad * 4 + r;
      s_red[wave][0][m][ln16] = a0[r];
      s_red[wave][1][m][ln16] = a1[r];
      s_red[wave][2][m][ln16] = a2[r];
    }
    if (ln16 == 0) {
#pragma unroll
      for (int r = 0; r < 4; ++r) s_x3[wave][quad * 4 + r] = a3[r];
    }
    __syncthreads();

    // x_i = x_{i-1} + dot(h_i, w_traj) + b_traj  (identical arithmetic in every
    // thread of every WG -> bitwise-identical x_reg; no LDS broadcast needed)
    if (i > 0) {
      const float xd = ((s_x3[0][eb] + s_x3[1][eb]) + s_x3[2][eb]) + s_x3[3][eb];
      x_reg += xd + bt;
    }
    if (i == Tsteps) {
      if (wg == 0 && ekc == 0) out[eb * Tsteps + (i - 1)] = x_reg;
      break;
    }

    // gates for (eb, ecol)
    const float gr = ((s_red[0][0][eb][ekc] + s_red[1][0][eb][ekc]) + s_red[2][0][eb][ekc]) + s_red[3][0][eb][ekc];
    const float gz = ((s_red[0][1][eb][ekc] + s_red[1][1][eb][ekc]) + s_red[2][1][eb][ekc]) + s_red[3][1][eb][ekc];
    const float gn = ((s_red[0][2][eb][ekc] + s_red[1][2][eb][ekc]) + s_red[2][2][eb][ekc]) + s_red[3][2][eb][ekc];
    const float x  = x_reg;
    const float rr = 1.f / (1.f + expf(-(x * wr + br + gr)));
    const float zz = 1.f / (1.f + expf(-(x * wz + bz + gz)));
    const float nn = tanhf(x * wn + bin + rr * (gn + bhn));
    h_own = (1.f - zz) * nn + zz * h_own;

    // publish h_{i+1}, then flag; wg0's out-store LAST (off the critical path)
    publish_h(hbuf32, (i + 1) & 1, eb, ekc, ecol, h_own);
    publish(flags, wg, tid, (uint32_t)(i + 2));
    if (wg == 0 && i > 0 && ekc == 0) out[eb * Tsteps + (i - 1)] = x_reg;
  }
}

extern "C" void kernel_launch(void* const* d_in, const int* in_sizes, int n_in,
                              void* d_out, int out_size, void* d_ws, size_t ws_size,
                              hipStream_t stream) {
  const float* traj_z     = (const float*)d_in[0];
  const float* traj_input = (const float*)d_in[1];
  const float* w_ih   = (const float*)d_in[2];
  const float* b_ih   = (const float*)d_in[3];
  const float* w_hh   = (const float*)d_in[4];
  const float* b_hh   = (const float*)d_in[5];
  const float* w_traj = (const float*)d_in[6];
  const float* b_traj = (const float*)d_in[7];
  float* out = (float*)d_out;

  uint8_t*  ws    = (uint8_t*)d_ws;
  uint32_t* flags = (uint32_t*)ws;                 // NREP * NWG * 128B = 64 KB
  uint32_t* hbuf  = (uint32_t*)(ws + NREP * NWG * FLAGSTRIDE * 4);  // 2*64KB = 128 KB

  (void)hipMemsetAsync(flags, 0, NREP * NWG * FLAGSTRIDE * 4, stream);
  hipLaunchKernelGGL(traj_kernel, dim3(NWG), dim3(TPB), 0, stream,
                     traj_z, traj_input, w_ih, b_ih, w_hh, b_hh, w_traj, b_traj,
                     out, hbuf, flags);
}

// Round 16
// 1616.644 us; speedup vs baseline: 1.6194x; 1.0426x over previous
//
#include <hip/hip_runtime.h>
#include <stdint.h>
#include <math.h>

// Problem constants (B, H, T) = (16, 2048, 512)
#define Hdim   2048
#define Bdim   16
#define Tsteps 512
#define NWG    128   // workgroups; each owns KC columns of h (R6-proven optimum)
#define TPB    256   // 4 waves
#define KC     16    // h-columns per WG  (NWG*KC == Hdim)
#define NCHUNK 16    // K-chunks of 32 per wave (wave K-range = 512)
#define FLAGSTRIDE 32  // uint32s between per-WG flags (128B) — separate lines
#define HBYTES (Bdim * Hdim * 2)   // one h buffer in bytes (fragment-major bf16)
#define NBUF   513   // write-once ring: one slot per step -> cached reads never stale
#define PSTRIDE 31   // slot permutation stride (coprime with 513; defeats prefetch)

typedef __attribute__((ext_vector_type(8))) short short8_t;  // 8 bf16 (4 VGPRs)
typedef __attribute__((ext_vector_type(4))) float f32x4;     // MFMA C/D
typedef __attribute__((ext_vector_type(4))) unsigned int u32x4;

__device__ __forceinline__ short f2bf(float x) {
  uint32_t u = __builtin_bit_cast(uint32_t, x);
  u += 0x7fffu + ((u >> 16) & 1u);   // RNE
  return (short)(u >> 16);
}

__device__ __forceinline__ short8_t load8_bf(const float* __restrict__ p) {
  short8_t r;
#pragma unroll
  for (int j = 0; j < 8; ++j) r[j] = f2bf(p[j]);
  return r;
}

// ---- flag barrier helpers (R6-proven protocol) ----
// publish: vmcnt(0) drains this wave's h-stores (inline-asm ones the compiler
// doesn't track), __syncthreads joins all waves (so the flag means ALL of this
// WG's h stores are LLC-visible), then one thread stores the arrival flag.
__device__ __forceinline__ void publish(uint32_t* flags, int wg, int tid, uint32_t n) {
  asm volatile("s_waitcnt vmcnt(0)" ::: "memory");
  __syncthreads();
  if (tid == 0)
    __hip_atomic_store(flags + wg * FLAGSTRIDE, n, __ATOMIC_RELAXED, __HIP_MEMORY_SCOPE_AGENT);
}

// wait_quarter: wave w only consumes h columns [512w, 512w+512), produced by
// WGs [32w, 32w+32). Poll exactly those 32 separated flag lines and proceed.
// RULE (R8): every load issued after this wait depends ONLY on those producers.
__device__ __forceinline__ void wait_quarter(const uint32_t* flags, int wave, int lane, uint32_t n) {
  if (lane < 32) {
    const uint32_t* f = flags + (wave * 32 + lane) * FLAGSTRIDE;
    while (__hip_atomic_load(f, __ATOMIC_RELAXED, __HIP_MEMORY_SCOPE_AGENT) < n) {
      __builtin_amdgcn_s_sleep(1);
    }
  }
  __builtin_amdgcn_sched_barrier(0);
}

// ---- h buffer layout (R3): MFMA-fragment-major ----
// 16B block (gc*4 + quad)*16 + batch holds cols [gc*32+quad*8, +8) of one batch.
// Byte offset of (b, col): (col>>3)*256 + b*16 + (col&7)*2.
// Producer stores sc0 sc1 (straight to LLC, the coherence point).
__device__ __forceinline__ void publish_h(char* dstbase, int eb, int ekc, int ecol, float h_own) {
  uint32_t mybits = (uint32_t)(uint16_t)f2bf(h_own);
  uint32_t n1 = (uint32_t)__shfl_xor((int)mybits, 1, 64);
  uint32_t a  = (mybits & 0xffffu) | (n1 << 16);            // cols j, j+1
  uint32_t b  = (uint32_t)__shfl_xor((int)a, 2, 64);        // cols j+2, j+3
  uint32_t c4 = (uint32_t)__shfl_xor((int)a, 4, 64);        // cols j+4, j+5
  uint32_t d  = (uint32_t)__shfl_xor((int)b, 4, 64);        // cols j+6, j+7
  if ((ekc & 7) == 0) {
    u32x4 q; q.x = a; q.y = b; q.z = c4; q.w = d;
    char* dst = dstbase + ((size_t)(ecol >> 3) * 256 + (size_t)eb * 16);
    asm volatile("global_store_dwordx4 %0, %1, off sc0 sc1" :: "v"(dst), "v"(q) : "memory");
  }
}

// Shared per-thread setup packed into a macro to keep the two kernels in sync.
#define KERNEL_PROLOGUE                                                          \
  const int tid  = threadIdx.x;                                                  \
  const int wg   = blockIdx.x;                                                   \
  const int wave = tid >> 6;                                                     \
  const int lane = tid & 63;                                                     \
  const int ln16 = lane & 15;                                                    \
  const int quad = lane >> 4;                                                    \
  const int colbase = wg * KC;                                                   \
  const int kwave   = wave * (Hdim / 4);                                         \
  __shared__ float s_red[4][3][16][16];                                          \
  __shared__ float s_x3[4][16];                                                  \
  short8_t wf0[NCHUNK], wf1[NCHUNK], wf2[NCHUNK], wt[NCHUNK];                    \
  _Pragma("unroll")                                                              \
  for (int c = 0; c < NCHUNK; ++c) {                                             \
    const int k0 = kwave + c * 32 + quad * 8;                                    \
    wf0[c] = load8_bf(w_hh + (size_t)(0 * Hdim + colbase + ln16) * Hdim + k0);   \
    wf1[c] = load8_bf(w_hh + (size_t)(1 * Hdim + colbase + ln16) * Hdim + k0);   \
    wf2[c] = load8_bf(w_hh + (size_t)(2 * Hdim + colbase + ln16) * Hdim + k0);   \
    short8_t g = {0, 0, 0, 0, 0, 0, 0, 0};                                       \
    if (ln16 == 0) g = load8_bf(w_traj + k0);                                    \
    wt[c] = g;                                                                   \
  }                                                                              \
  const int eb   = tid >> 4;                                                     \
  const int ekc  = tid & 15;                                                     \
  const int ecol = colbase + ekc;                                                \
  const float wr = w_ih[ecol], wz = w_ih[Hdim + ecol], wn = w_ih[2 * Hdim + ecol];\
  const float br = b_ih[ecol] + b_hh[ecol];                                      \
  const float bz = b_ih[Hdim + ecol] + b_hh[Hdim + ecol];                        \
  const float bin = b_ih[2 * Hdim + ecol];                                       \
  const float bhn = b_hh[2 * Hdim + ecol];                                       \
  const float bt  = b_traj[0];                                                   \
  float h_own = traj_z[eb * Hdim + ecol];                                        \
  float x_reg = traj_input[eb * Tsteps];

#define MFMA_GROUP(G, VM)                                                      \
    asm volatile("s_waitcnt vmcnt(" #VM ")" ::: "memory");                     \
    __builtin_amdgcn_sched_barrier(0);                                         \
    _Pragma("unroll")                                                          \
    for (int c = (G) * 4; c < (G) * 4 + 4; ++c) {                              \
      a0 = __builtin_amdgcn_mfma_f32_16x16x32_bf16(af[c], wf0[c], a0, 0, 0, 0);\
      a1 = __builtin_amdgcn_mfma_f32_16x16x32_bf16(af[c], wf1[c], a1, 0, 0, 0);\
      a2 = __builtin_amdgcn_mfma_f32_16x16x32_bf16(af[c], wf2[c], a2, 0, 0, 0);\
      a3 = __builtin_amdgcn_mfma_f32_16x16x32_bf16(af[c], wt[c],  a3, 0, 0, 0);\
    }

#define KERNEL_TAIL                                                              \
    _Pragma("unroll")                                                            \
    for (int r = 0; r < 4; ++r) {                                                \
      const int m = quad * 4 + r;                                                \
      s_red[wave][0][m][ln16] = a0[r];                                           \
      s_red[wave][1][m][ln16] = a1[r];                                           \
      s_red[wave][2][m][ln16] = a2[r];                                           \
    }                                                                            \
    if (ln16 == 0) {                                                             \
      _Pragma("unroll")                                                          \
      for (int r = 0; r < 4; ++r) s_x3[wave][quad * 4 + r] = a3[r];              \
    }                                                                            \
    __syncthreads();                                                             \
    if (i > 0) {                                                                 \
      const float xd = ((s_x3[0][eb] + s_x3[1][eb]) + s_x3[2][eb]) + s_x3[3][eb];\
      x_reg += xd + bt;                                                          \
    }                                                                            \
    if (i == Tsteps) {                                                           \
      if (wg == 0 && ekc == 0) out[eb * Tsteps + (i - 1)] = x_reg;               \
      break;                                                                     \
    }                                                                            \
    const float gr = ((s_red[0][0][eb][ekc] + s_red[1][0][eb][ekc]) + s_red[2][0][eb][ekc]) + s_red[3][0][eb][ekc]; \
    const float gz = ((s_red[0][1][eb][ekc] + s_red[1][1][eb][ekc]) + s_red[2][1][eb][ekc]) + s_red[3][1][eb][ekc]; \
    const float gn = ((s_red[0][2][eb][ekc] + s_red[1][2][eb][ekc]) + s_red[2][2][eb][ekc]) + s_red[3][2][eb][ekc]; \
    const float x  = x_reg;                                                      \
    const float rr = 1.f / (1.f + expf(-(x * wr + br + gr)));                    \
    const float zz = 1.f / (1.f + expf(-(x * wz + bz + gz)));                    \
    const float nn = tanhf(x * wn + bin + rr * (gn + bhn));                      \
    h_own = (1.f - zz) * nn + zz * h_own;

// ================= RING kernel: write-once slots, CACHED consumer reads ======
// Slot perm(i) = (i*31) % 513 holds h_i. Lines of each slot are COLD until the
// producer's single sc0sc1 write -> a cached read can never hit stale data; the
// L2 miss fetches the post-write line from LLC. 16 WGs/XCD share each 64KB h
// through their L2 -> LLC traffic drops 16x vs the uncached all-to-all.
__global__ void __launch_bounds__(TPB, 1) traj_kernel_ring(
    const float* __restrict__ traj_z, const float* __restrict__ traj_input,
    const float* __restrict__ w_ih, const float* __restrict__ b_ih,
    const float* __restrict__ w_hh, const float* __restrict__ b_hh,
    const float* __restrict__ w_traj, const float* __restrict__ b_traj,
    float* __restrict__ out, char* __restrict__ ring, uint32_t* __restrict__ flags)
{
  KERNEL_PROLOGUE

  publish_h(ring /*slot 0*/, eb, ekc, ecol, h_own);
  publish(flags, wg, tid, 1);

  int rd = 0;   // perm(i): current read slot
  for (int i = 0; i <= Tsteps; ++i) {
    wait_quarter(flags, wave, lane, (uint32_t)(i + 1));
    asm volatile("s_waitcnt vmcnt(0)" ::: "memory");  // vmcnt bookkeeping exact

    // CACHED coalesced loads of h_i (cold lines -> L2 miss -> fresh LLC fetch;
    // subsequent WGs on this XCD hit L2). Counted-vmcnt overlap as R6.
    const char* hbase = ring + (size_t)rd * HBYTES
                      + (size_t)(kwave >> 5) * 1024 + (size_t)lane * 16;
    short8_t af[NCHUNK];
#pragma unroll
    for (int c = 0; c < NCHUNK; ++c) {
      asm volatile("global_load_dwordx4 %0, %1, off"
                   : "=v"(af[c]) : "v"(hbase + (size_t)c * 1024));
    }

    f32x4 a0 = {0.f, 0.f, 0.f, 0.f}, a1 = a0, a2 = a0, a3 = a0;
    MFMA_GROUP(0, 12)
    MFMA_GROUP(1, 8)
    MFMA_GROUP(2, 4)
    MFMA_GROUP(3, 0)

    KERNEL_TAIL

    int wr_slot = rd + PSTRIDE; if (wr_slot >= NBUF) wr_slot -= NBUF;  // perm(i+1)
    publish_h(ring + (size_t)wr_slot * HBYTES, eb, ekc, ecol, h_own);
    publish(flags, wg, tid, (uint32_t)(i + 2));
    if (wg == 0 && i > 0 && ekc == 0) out[eb * Tsteps + (i - 1)] = x_reg;
    rd = wr_slot;
  }
}

// ================= BASE kernel: R12-proven 2-buffer uncached protocol ========
// Fallback when ws_size can't fit the ring (byte-identical to the 1609us R6/R12
// structure: parity double-buffer, sc0sc1 uncached consumer loads).
__global__ void __launch_bounds__(TPB, 1) traj_kernel_base(
    const float* __restrict__ traj_z, const float* __restrict__ traj_input,
    const float* __restrict__ w_ih, const float* __restrict__ b_ih,
    const float* __restrict__ w_hh, const float* __restrict__ b_hh,
    const float* __restrict__ w_traj, const float* __restrict__ b_traj,
    float* __restrict__ out, char* __restrict__ hbuf, uint32_t* __restrict__ flags)
{
  KERNEL_PROLOGUE

  publish_h(hbuf /*parity 0*/, eb, ekc, ecol, h_own);
  publish(flags, wg, tid, 1);

  for (int i = 0; i <= Tsteps; ++i) {
    wait_quarter(flags, wave, lane, (uint32_t)(i + 1));
    asm volatile("s_waitcnt vmcnt(0)" ::: "memory");

    const char* hbase = hbuf + (size_t)(i & 1) * HBYTES
                      + (size_t)(kwave >> 5) * 1024 + (size_t)lane * 16;
    short8_t af[NCHUNK];
#pragma unroll
    for (int c = 0; c < NCHUNK; ++c) {
      asm volatile("global_load_dwordx4 %0, %1, off sc0 sc1"
                   : "=v"(af[c]) : "v"(hbase + (size_t)c * 1024));
    }

    f32x4 a0 = {0.f, 0.f, 0.f, 0.f}, a1 = a0, a2 = a0, a3 = a0;
    MFMA_GROUP(0, 12)
    MFMA_GROUP(1, 8)
    MFMA_GROUP(2, 4)
    MFMA_GROUP(3, 0)

    KERNEL_TAIL

    publish_h(hbuf + (size_t)((i + 1) & 1) * HBYTES, eb, ekc, ecol, h_own);
    publish(flags, wg, tid, (uint32_t)(i + 2));
    if (wg == 0 && i > 0 && ekc == 0) out[eb * Tsteps + (i - 1)] = x_reg;
  }
}

extern "C" void kernel_launch(void* const* d_in, const int* in_sizes, int n_in,
                              void* d_out, int out_size, void* d_ws, size_t ws_size,
                              hipStream_t stream) {
  const float* traj_z     = (const float*)d_in[0];
  const float* traj_input = (const float*)d_in[1];
  const float* w_ih   = (const float*)d_in[2];
  const float* b_ih   = (const float*)d_in[3];
  const float* w_hh   = (const float*)d_in[4];
  const float* b_hh   = (const float*)d_in[5];
  const float* w_traj = (const float*)d_in[6];
  const float* b_traj = (const float*)d_in[7];
  float* out = (float*)d_out;

  uint8_t*  ws    = (uint8_t*)d_ws;
  uint32_t* flags = (uint32_t*)ws;                 // NWG*FLAGSTRIDE u32 = 16 KB
  char*     hbuf  = (char*)(ws + 16384);

  (void)hipMemsetAsync(flags, 0, NWG * FLAGSTRIDE * 4, stream);

  const size_t ring_need = 16384ull + (size_t)NBUF * HBYTES;  // ~33.7 MB
  if (ws_size >= ring_need) {
    hipLaunchKernelGGL(traj_kernel_ring, dim3(NWG), dim3(TPB), 0, stream,
                       traj_z, traj_input, w_ih, b_ih, w_hh, b_hh, w_traj, b_traj,
                       out, hbuf, flags);
  } else {
    hipLaunchKernelGGL(traj_kernel_base, dim3(NWG), dim3(TPB), 0, stream,
                       traj_z, traj_input, w_ih, b_ih, w_hh, b_hh, w_traj, b_traj,
                       out, hbuf, flags);
  }
}